// Round 4
// baseline (465.960 us; speedup 1.0000x reference)
//
#include <hip/hip_runtime.h>
#include <math.h>

#define S_ 64
#define E_ 2048
#define H_ 32
#define D_ 64
#define L_ 2048
#define BS_ 16
#define BPS_ 128
#define QKV_N (3 * E_)   // 6144
#define CHUNK_TOK 256    // tokens per chunk (16 cache blocks)
#define CHUNK_BLKS 16
#define MAXCH 8          // max chunks per (seq, head): L / CHUNK_TOK

// ---------------------------------------------------------------------------
// Tall-skinny GEMM: C[64,N] += A[64,K] @ B[K,N] (+ bias added by k-chunk 0).
// grid = (N/128, KSPLIT); block = 256. Thread: 2 consecutive cols x 16 rows.
// A tile in LDS, read as wave-uniform ds_read_b128 broadcast. UNCHANGED from
// R3 (isolating the attention change this round).
// ---------------------------------------------------------------------------
__global__ __launch_bounds__(256) void gemm64(const float* __restrict__ A,
                                              const float* __restrict__ B,
                                              const float* __restrict__ bias,
                                              float* __restrict__ C,
                                              int K, int N) {
    __shared__ float As[64][32];
    const int t    = threadIdx.x;
    const int lane = t & 63;
    const int mg   = t >> 6;                // wave id = row group (16 rows)
    const int colbase = blockIdx.x * 128 + lane * 2;
    const int kchunk  = K / gridDim.y;
    const int ks      = blockIdx.y * kchunk;

    float2 acc[16];
    if (blockIdx.y == 0) {
        float2 bb = *(const float2*)(bias + colbase);
#pragma unroll
        for (int mm = 0; mm < 16; ++mm) acc[mm] = bb;
    } else {
#pragma unroll
        for (int mm = 0; mm < 16; ++mm) acc[mm] = make_float2(0.f, 0.f);
    }

    for (int k0 = ks; k0 < ks + kchunk; k0 += 32) {
        __syncthreads();
#pragma unroll
        for (int i = 0; i < 2; ++i) {       // 512 float4 = 64 rows x 32 k
            int f4  = t + i * 256;
            int row = f4 >> 3, c4 = f4 & 7;
            *(float4*)&As[row][c4 * 4] =
                *(const float4*)(A + (size_t)row * K + k0 + c4 * 4);
        }
        __syncthreads();
#pragma unroll
        for (int kk = 0; kk < 32; kk += 4) {
            float2 b0 = *(const float2*)(B + (size_t)(k0 + kk + 0) * N + colbase);
            float2 b1 = *(const float2*)(B + (size_t)(k0 + kk + 1) * N + colbase);
            float2 b2 = *(const float2*)(B + (size_t)(k0 + kk + 2) * N + colbase);
            float2 b3 = *(const float2*)(B + (size_t)(k0 + kk + 3) * N + colbase);
#pragma unroll
            for (int mm = 0; mm < 16; ++mm) {
                float4 a = *(const float4*)&As[mg * 16 + mm][kk];
                acc[mm].x = fmaf(a.x, b0.x, acc[mm].x);
                acc[mm].y = fmaf(a.x, b0.y, acc[mm].y);
                acc[mm].x = fmaf(a.y, b1.x, acc[mm].x);
                acc[mm].y = fmaf(a.y, b1.y, acc[mm].y);
                acc[mm].x = fmaf(a.z, b2.x, acc[mm].x);
                acc[mm].y = fmaf(a.z, b2.y, acc[mm].y);
                acc[mm].x = fmaf(a.w, b3.x, acc[mm].x);
                acc[mm].y = fmaf(a.w, b3.y, acc[mm].y);
            }
        }
    }
#pragma unroll
    for (int mm = 0; mm < 16; ++mm) {
        float* cp = C + (size_t)(mg * 16 + mm) * N + colbase;
        atomicAdd(cp + 0, acc[mm].x);
        atomicAdd(cp + 1, acc[mm].y);
    }
}

// ---------------------------------------------------------------------------
// Paged attention, stage 1: fixed-size chunks for load balance.
// One wave = one 256-token chunk of one (seq, head). grid = 8192 blocks of
// 128 threads (2 waves; chunk = (bid&3)*2 + waveid). ~13k real chunks over
// 8192 wave slots -> ~1.6 rounds of equal-size units (dynamic rebalance).
// Lane = g*8+j: g = token sub-slot (0..7), j = eighth of head_dim. Per-group
// online softmax; flash-merge the 8 groups at the end; write (m,l,acc[64])
// partial to workspace. No LDS, no syncthreads.
// ---------------------------------------------------------------------------
__global__ __launch_bounds__(128, 6) void attn_chunk(
        const float* __restrict__ qkv,
        const float* __restrict__ kcache,
        const float* __restrict__ vcache,
        const int* __restrict__ btab,
        const int* __restrict__ clens,
        float* __restrict__ ml,        // [S*H][MAXCH][2]
        float* __restrict__ pacc) {    // [S*H][MAXCH][64]
    const int bid = blockIdx.x;
    const int sh  = bid >> 2;
    const int t   = threadIdx.x;
    const int w   = t >> 6;
    const int c   = ((bid & 3) << 1) | w;   // chunk 0..7
    const int s   = sh >> 5;
    const int h   = sh & 31;
    const int ctx = clens[s];
    if (c * CHUNK_TOK >= ctx) return;        // empty chunk: free the slot

    const int lane = t & 63;
    const int g    = lane >> 3;
    const int j    = lane & 7;
    const float scale = 0.125f;

    const float* qp = qkv + (size_t)s * QKV_N + h * 64 + j * 8;
    const float4 q0 = *(const float4*)(qp);
    const float4 q1 = *(const float4*)(qp + 4);

    float m = -1e30f, l = 0.f;
    float4 a0 = make_float4(0.f, 0.f, 0.f, 0.f);
    float4 a1 = make_float4(0.f, 0.f, 0.f, 0.f);

    const int* bt   = btab + s * BPS_;
    const int  hoff = h * 64 + j * 8;
    const int  bend = min(c * CHUNK_BLKS + CHUNK_BLKS, (ctx + 15) >> 4);

    for (int b = c * CHUNK_BLKS; b < bend; ++b) {
        const int blk = bt[b];
        const size_t blkbase = (size_t)blk * (BS_ * H_ * D_) + hoff;
#pragma unroll
        for (int half = 0; half < 2; ++half) {
            const size_t base = blkbase + (size_t)(half * 8 + g) * (H_ * D_);
            const float* kp = kcache + base;
            const float* vp = vcache + base;
            const float4 k0 = *(const float4*)(kp);
            const float4 k1 = *(const float4*)(kp + 4);
            const float4 v0 = *(const float4*)(vp);
            const float4 v1 = *(const float4*)(vp + 4);

            float part = q0.x * k0.x + q0.y * k0.y + q0.z * k0.z + q0.w * k0.w
                       + q1.x * k1.x + q1.y * k1.y + q1.z * k1.z + q1.w * k1.w;
            part += __shfl_xor(part, 1);
            part += __shfl_xor(part, 2);
            part += __shfl_xor(part, 4);

            const int tok = b * 16 + half * 8 + g;
            const float score = (tok < ctx) ? part * scale : -1e38f;
            const float nm = fmaxf(m, score);
            const float r  = __expf(m - nm);
            const float p  = __expf(score - nm);
            m = nm;
            l = fmaf(l, r, p);
            a0.x = fmaf(p, v0.x, a0.x * r);
            a0.y = fmaf(p, v0.y, a0.y * r);
            a0.z = fmaf(p, v0.z, a0.z * r);
            a0.w = fmaf(p, v0.w, a0.w * r);
            a1.x = fmaf(p, v1.x, a1.x * r);
            a1.y = fmaf(p, v1.y, a1.y * r);
            a1.z = fmaf(p, v1.z, a1.z * r);
            a1.w = fmaf(p, v1.w, a1.w * r);
        }
    }

    // flash-merge the 8 token-groups (lane bits 3..5)
#pragma unroll
    for (int msk = 8; msk <= 32; msk <<= 1) {
        float om = __shfl_xor(m, msk);
        float ol = __shfl_xor(l, msk);
        float nm = fmaxf(m, om);
        float ra = __expf(m - nm);
        float rb = __expf(om - nm);
        l = ra * l + rb * ol;
        a0.x = ra * a0.x + rb * __shfl_xor(a0.x, msk);
        a0.y = ra * a0.y + rb * __shfl_xor(a0.y, msk);
        a0.z = ra * a0.z + rb * __shfl_xor(a0.z, msk);
        a0.w = ra * a0.w + rb * __shfl_xor(a0.w, msk);
        a1.x = ra * a1.x + rb * __shfl_xor(a1.x, msk);
        a1.y = ra * a1.y + rb * __shfl_xor(a1.y, msk);
        a1.z = ra * a1.z + rb * __shfl_xor(a1.z, msk);
        a1.w = ra * a1.w + rb * __shfl_xor(a1.w, msk);
        m = nm;
    }

    const int slot = sh * MAXCH + c;
    if (g == 0) {                        // lanes 0..7 hold the 64 dims
        *(float4*)&pacc[(size_t)slot * 64 + j * 8]     = a0;
        *(float4*)&pacc[(size_t)slot * 64 + j * 8 + 4] = a1;
    }
    if (lane == 0) {
        ml[slot * 2 + 0] = m;
        ml[slot * 2 + 1] = l;
    }
}

// ---------------------------------------------------------------------------
// Paged attention, stage 2: merge <=8 chunk partials + the new token.
// One wave per (seq, head); thread d owns output dim d.
// ---------------------------------------------------------------------------
__global__ __launch_bounds__(64) void attn_merge(
        const float* __restrict__ qkv,
        const int* __restrict__ clens,
        const float* __restrict__ ml,
        const float* __restrict__ pacc,
        float* __restrict__ attn) {
    const int sh = blockIdx.x;
    const int s  = sh >> 5;
    const int h  = sh & 31;
    const int d  = threadIdx.x;
    const int ctx = clens[s];
    const int nch = (ctx + CHUNK_TOK - 1) / CHUNK_TOK;

    float M = -1e30f, L = 0.f, O = 0.f;
    for (int c = 0; c < nch; ++c) {
        const int slot = sh * MAXCH + c;
        const float mc = ml[slot * 2 + 0];
        const float lc = ml[slot * 2 + 1];
        const float oc = pacc[(size_t)slot * 64 + d];
        const float nm = fmaxf(M, mc);
        const float ra = __expf(M - nm);
        const float rb = __expf(mc - nm);
        O = O * ra + oc * rb;
        L = L * ra + lc * rb;
        M = nm;
    }

    // current token (position L_, always attended)
    const float qd = qkv[(size_t)s * QKV_N + h * 64 + d];
    const float kd = qkv[(size_t)s * QKV_N + E_ + h * 64 + d];
    float part = qd * kd;
#pragma unroll
    for (int msk = 1; msk <= 32; msk <<= 1) part += __shfl_xor(part, msk);
    const float score = part * 0.125f;   // uniform across the wave
    const float nm = fmaxf(M, score);
    const float r  = __expf(M - nm);
    const float p  = __expf(score - nm);
    const float vd = qkv[(size_t)s * QKV_N + 2 * E_ + h * 64 + d];
    O = O * r + p * vd;
    L = L * r + p;

    attn[(size_t)s * E_ + h * 64 + d] = O / L;
}

// ---------------------------------------------------------------------------
extern "C" void kernel_launch(void* const* d_in, const int* in_sizes, int n_in,
                              void* d_out, int out_size, void* d_ws, size_t ws_size,
                              hipStream_t stream) {
    const float* hidden = (const float*)d_in[0];
    const float* wqkv   = (const float*)d_in[1];
    const float* bqkv   = (const float*)d_in[2];
    const float* wout   = (const float*)d_in[3];
    const float* bout   = (const float*)d_in[4];
    const float* kcache = (const float*)d_in[5];
    const float* vcache = (const float*)d_in[6];
    const int*   btab   = (const int*)d_in[7];
    const int*   clens  = (const int*)d_in[8];
    float* out = (float*)d_out;

    float* qkv     = (float*)d_ws;                       // [64, 6144]
    float* attnbuf = qkv + (size_t)S_ * QKV_N;           // [64, 2048]
    float* ml      = attnbuf + (size_t)S_ * E_;          // [2048*8*2]
    float* pacc    = ml + (size_t)S_ * H_ * MAXCH * 2;   // [2048*8*64]

    hipMemsetAsync(qkv, 0, (size_t)S_ * QKV_N * sizeof(float), stream);
    hipMemsetAsync(out, 0, (size_t)S_ * E_ * sizeof(float), stream);

    // 1) fused QKV projection: [64,2048] x [2048,6144] + bias
    gemm64<<<dim3(QKV_N / 128, 8), 256, 0, stream>>>(hidden, wqkv, bqkv, qkv,
                                                     E_, QKV_N);
    // 2a) chunked paged attention -> partials
    attn_chunk<<<dim3(S_ * H_ * 4), 128, 0, stream>>>(qkv, kcache, vcache,
                                                      btab, clens, ml, pacc);
    // 2b) merge partials + new token -> attnbuf [64, 2048]
    attn_merge<<<dim3(S_ * H_), 64, 0, stream>>>(qkv, clens, ml, pacc, attnbuf);
    // 3) output projection: [64,2048] x [2048,2048] + bias -> d_out
    gemm64<<<dim3(E_ / 128, 16), 256, 0, stream>>>(attnbuf, wout, bout, out,
                                                   E_, E_);
}

// Round 5
// 395.192 us; speedup vs baseline: 1.1791x; 1.1791x over previous
//
#include <hip/hip_runtime.h>
#include <math.h>

#define S_ 64
#define E_ 2048
#define H_ 32
#define D_ 64
#define L_ 2048
#define BS_ 16
#define BPS_ 128
#define QKV_N (3 * E_)   // 6144

// ---------------------------------------------------------------------------
// Tall-skinny GEMM, stage 1: P[ky][64][N] = A[64,ks:ks+kc] @ B[ks:ks+kc, N].
// Plain stores, no atomics. grid = (N/128, KSPLIT); block = 256.
// Thread: 2 consecutive cols x 16 rows. A tile in LDS, wave-uniform
// ds_read_b128 broadcast.
// ---------------------------------------------------------------------------
__global__ __launch_bounds__(256) void gemm_part(const float* __restrict__ A,
                                                 const float* __restrict__ B,
                                                 float* __restrict__ P,
                                                 int K, int N) {
    __shared__ float As[64][32];
    const int t    = threadIdx.x;
    const int lane = t & 63;
    const int mg   = t >> 6;                // wave id = row group (16 rows)
    const int colbase = blockIdx.x * 128 + lane * 2;
    const int kchunk  = K / gridDim.y;
    const int ks      = blockIdx.y * kchunk;

    float2 acc[16];
#pragma unroll
    for (int mm = 0; mm < 16; ++mm) acc[mm] = make_float2(0.f, 0.f);

    for (int k0 = ks; k0 < ks + kchunk; k0 += 32) {
        __syncthreads();
#pragma unroll
        for (int i = 0; i < 2; ++i) {       // 512 float4 = 64 rows x 32 k
            int f4  = t + i * 256;
            int row = f4 >> 3, c4 = f4 & 7;
            *(float4*)&As[row][c4 * 4] =
                *(const float4*)(A + (size_t)row * K + k0 + c4 * 4);
        }
        __syncthreads();
#pragma unroll
        for (int kk = 0; kk < 32; kk += 4) {
            float2 b0 = *(const float2*)(B + (size_t)(k0 + kk + 0) * N + colbase);
            float2 b1 = *(const float2*)(B + (size_t)(k0 + kk + 1) * N + colbase);
            float2 b2 = *(const float2*)(B + (size_t)(k0 + kk + 2) * N + colbase);
            float2 b3 = *(const float2*)(B + (size_t)(k0 + kk + 3) * N + colbase);
#pragma unroll
            for (int mm = 0; mm < 16; ++mm) {
                float4 a = *(const float4*)&As[mg * 16 + mm][kk];
                acc[mm].x = fmaf(a.x, b0.x, acc[mm].x);
                acc[mm].y = fmaf(a.x, b0.y, acc[mm].y);
                acc[mm].x = fmaf(a.y, b1.x, acc[mm].x);
                acc[mm].y = fmaf(a.y, b1.y, acc[mm].y);
                acc[mm].x = fmaf(a.z, b2.x, acc[mm].x);
                acc[mm].y = fmaf(a.z, b2.y, acc[mm].y);
                acc[mm].x = fmaf(a.w, b3.x, acc[mm].x);
                acc[mm].y = fmaf(a.w, b3.y, acc[mm].y);
            }
        }
    }
    float* Pb = P + (size_t)blockIdx.y * 64 * N;
#pragma unroll
    for (int mm = 0; mm < 16; ++mm)
        *(float2*)(Pb + (size_t)(mg * 16 + mm) * N + colbase) = acc[mm];
}

// ---------------------------------------------------------------------------
// Stage 2: C[64][N] = bias + sum_k P[k][64][N].  float4 per thread.
// grid = 64*N/4/256 blocks exactly.
// ---------------------------------------------------------------------------
__global__ __launch_bounds__(256) void reduce_add(const float* __restrict__ P,
                                                  const float* __restrict__ bias,
                                                  float* __restrict__ C,
                                                  int N, int nparts) {
    const int i4     = blockIdx.x * 256 + threadIdx.x;
    const int total4 = 64 * N / 4;
    const int col4   = i4 % (N / 4);
    float4 s = ((const float4*)bias)[col4];
    for (int k = 0; k < nparts; ++k) {
        float4 p = ((const float4*)P)[(size_t)k * total4 + i4];
        s.x += p.x; s.y += p.y; s.z += p.z; s.w += p.w;
    }
    ((float4*)C)[i4] = s;
}

// ---------------------------------------------------------------------------
// Paged decode attention — UNCHANGED from R3 (best measured variant).
// One block per (seq, head); 4 waves, K-split by 4 within the block.
// Lane = g*8+j. Per-group online softmax; flash-merge (xor 8/16/32);
// new-token on wave 0; LDS merge of 4 waves.
// ---------------------------------------------------------------------------
__global__ __launch_bounds__(256, 6) void paged_attn(
        const float* __restrict__ qkv,
        const float* __restrict__ kcache,
        const float* __restrict__ vcache,
        const int* __restrict__ btab,
        const int* __restrict__ clens,
        float* __restrict__ attn) {
    const int bid  = blockIdx.x;
    const int s    = bid >> 5;
    const int h    = bid & 31;
    const int t    = threadIdx.x;
    const int w    = t >> 6;
    const int lane = t & 63;
    const int g    = lane >> 3;         // token sub-slot
    const int j    = lane & 7;          // eighth of head_dim
    const int ctx  = clens[s];
    const int nb   = (ctx + 15) >> 4;
    const float scale = 0.125f;

    const float* qp = qkv + (size_t)s * QKV_N + h * 64 + j * 8;
    const float4 q0 = *(const float4*)(qp);
    const float4 q1 = *(const float4*)(qp + 4);

    float m = -1e30f, l = 0.f;
    float4 a0 = make_float4(0.f, 0.f, 0.f, 0.f);
    float4 a1 = make_float4(0.f, 0.f, 0.f, 0.f);

    const int* bt   = btab + s * BPS_;
    const int  hoff = h * 64 + j * 8;

    for (int b = w; b < nb; b += 4) {
        const int blk = bt[b];
        const size_t blkbase = (size_t)blk * (BS_ * H_ * D_) + hoff;
#pragma unroll
        for (int half = 0; half < 2; ++half) {
            const size_t base = blkbase + (size_t)(half * 8 + g) * (H_ * D_);
            const float* kp = kcache + base;
            const float* vp = vcache + base;
            const float4 k0 = *(const float4*)(kp);
            const float4 k1 = *(const float4*)(kp + 4);
            const float4 v0 = *(const float4*)(vp);
            const float4 v1 = *(const float4*)(vp + 4);

            float part = q0.x * k0.x + q0.y * k0.y + q0.z * k0.z + q0.w * k0.w
                       + q1.x * k1.x + q1.y * k1.y + q1.z * k1.z + q1.w * k1.w;
            part += __shfl_xor(part, 1);
            part += __shfl_xor(part, 2);
            part += __shfl_xor(part, 4);

            const int tok = b * 16 + half * 8 + g;
            const float score = (tok < ctx) ? part * scale : -1e38f;
            const float nm = fmaxf(m, score);
            const float r  = __expf(m - nm);
            const float p  = __expf(score - nm);
            m = nm;
            l = fmaf(l, r, p);
            a0.x = fmaf(p, v0.x, a0.x * r);
            a0.y = fmaf(p, v0.y, a0.y * r);
            a0.z = fmaf(p, v0.z, a0.z * r);
            a0.w = fmaf(p, v0.w, a0.w * r);
            a1.x = fmaf(p, v1.x, a1.x * r);
            a1.y = fmaf(p, v1.y, a1.y * r);
            a1.z = fmaf(p, v1.z, a1.z * r);
            a1.w = fmaf(p, v1.w, a1.w * r);
        }
    }

#pragma unroll
    for (int msk = 8; msk <= 32; msk <<= 1) {
        float om = __shfl_xor(m, msk);
        float ol = __shfl_xor(l, msk);
        float nm = fmaxf(m, om);
        float ra = __expf(m - nm);
        float rb = __expf(om - nm);
        l = ra * l + rb * ol;
        a0.x = ra * a0.x + rb * __shfl_xor(a0.x, msk);
        a0.y = ra * a0.y + rb * __shfl_xor(a0.y, msk);
        a0.z = ra * a0.z + rb * __shfl_xor(a0.z, msk);
        a0.w = ra * a0.w + rb * __shfl_xor(a0.w, msk);
        a1.x = ra * a1.x + rb * __shfl_xor(a1.x, msk);
        a1.y = ra * a1.y + rb * __shfl_xor(a1.y, msk);
        a1.z = ra * a1.z + rb * __shfl_xor(a1.z, msk);
        a1.w = ra * a1.w + rb * __shfl_xor(a1.w, msk);
        m = nm;
    }

    if (w == 0) {
        const float* kn = qkv + (size_t)s * QKV_N + E_ + h * 64 + j * 8;
        const float* vn = qkv + (size_t)s * QKV_N + 2 * E_ + h * 64 + j * 8;
        const float4 k0 = *(const float4*)(kn);
        const float4 k1 = *(const float4*)(kn + 4);
        float part = q0.x * k0.x + q0.y * k0.y + q0.z * k0.z + q0.w * k0.w
                   + q1.x * k1.x + q1.y * k1.y + q1.z * k1.z + q1.w * k1.w;
        part += __shfl_xor(part, 1);
        part += __shfl_xor(part, 2);
        part += __shfl_xor(part, 4);
        const float score = part * scale;
        const float nm = fmaxf(m, score);
        const float r  = __expf(m - nm);
        const float p  = __expf(score - nm);
        l = fmaf(l, r, p);
        const float4 v0 = *(const float4*)(vn);
        const float4 v1 = *(const float4*)(vn + 4);
        a0.x = fmaf(p, v0.x, a0.x * r);
        a0.y = fmaf(p, v0.y, a0.y * r);
        a0.z = fmaf(p, v0.z, a0.z * r);
        a0.w = fmaf(p, v0.w, a0.w * r);
        a1.x = fmaf(p, v1.x, a1.x * r);
        a1.y = fmaf(p, v1.y, a1.y * r);
        a1.z = fmaf(p, v1.z, a1.z * r);
        a1.w = fmaf(p, v1.w, a1.w * r);
        m = nm;
    }

    __shared__ float lm[4], ll[4], la[4][64];
    if (g == 0) {
        *(float4*)&la[w][j * 8]     = a0;
        *(float4*)&la[w][j * 8 + 4] = a1;
    }
    if (lane == 0) { lm[w] = m; ll[w] = l; }
    __syncthreads();

    if (t < 64) {
        const int d = t;
        float M = fmaxf(fmaxf(lm[0], lm[1]), fmaxf(lm[2], lm[3]));
        float Lsum = 0.f, o = 0.f;
#pragma unroll
        for (int ww = 0; ww < 4; ++ww) {
            float f = __expf(lm[ww] - M);
            Lsum += f * ll[ww];
            o += f * la[ww][d];
        }
        attn[(size_t)s * E_ + h * 64 + d] = o / Lsum;
    }
}

// ---------------------------------------------------------------------------
extern "C" void kernel_launch(void* const* d_in, const int* in_sizes, int n_in,
                              void* d_out, int out_size, void* d_ws, size_t ws_size,
                              hipStream_t stream) {
    const float* hidden = (const float*)d_in[0];
    const float* wqkv   = (const float*)d_in[1];
    const float* bqkv   = (const float*)d_in[2];
    const float* wout   = (const float*)d_in[3];
    const float* bout   = (const float*)d_in[4];
    const float* kcache = (const float*)d_in[5];
    const float* vcache = (const float*)d_in[6];
    const int*   btab   = (const int*)d_in[7];
    const int*   clens  = (const int*)d_in[8];
    float* out = (float*)d_out;

    float* qkv     = (float*)d_ws;                        // [64, 6144]
    float* attnbuf = qkv + (size_t)S_ * QKV_N;            // [64, 2048]
    float* part1   = attnbuf + (size_t)S_ * E_;           // [8][64][6144]
    float* part2   = part1 + (size_t)8 * S_ * QKV_N;      // [16][64][2048]

    // 1) QKV projection: partials (KSPLIT=8, 384 blocks) then reduce+bias
    gemm_part<<<dim3(QKV_N / 128, 8), 256, 0, stream>>>(hidden, wqkv, part1,
                                                        E_, QKV_N);
    reduce_add<<<dim3(S_ * QKV_N / 4 / 256), 256, 0, stream>>>(part1, bqkv,
                                                               qkv, QKV_N, 8);
    // 2) paged attention -> attnbuf [64, 2048]
    paged_attn<<<dim3(S_ * H_), 256, 0, stream>>>(qkv, kcache, vcache, btab,
                                                  clens, attnbuf);
    // 3) output projection: partials (KSPLIT=16, 256 blocks) then reduce+bias
    gemm_part<<<dim3(E_ / 128, 16), 256, 0, stream>>>(attnbuf, wout, part2,
                                                      E_, E_);
    reduce_add<<<dim3(S_ * E_ / 4 / 256), 256, 0, stream>>>(part2, bout,
                                                            out, E_, 16);
}

// Round 6
// 387.478 us; speedup vs baseline: 1.2025x; 1.0199x over previous
//
#include <hip/hip_runtime.h>
#include <math.h>

#define S_ 64
#define E_ 2048
#define H_ 32
#define D_ 64
#define L_ 2048
#define BS_ 16
#define BPS_ 128
#define QKV_N (3 * E_)   // 6144
#define CHUNK_CB 8       // cache blocks per chunk (= 128 tokens)
#define MAXCH 16         // max chunks per seq

// ---------------------------------------------------------------------------
// Tall-skinny GEMM, stage 1 (UNCHANGED from R5): P[ky][64][N] = A @ B-chunk.
// ---------------------------------------------------------------------------
__global__ __launch_bounds__(256) void gemm_part(const float* __restrict__ A,
                                                 const float* __restrict__ B,
                                                 float* __restrict__ P,
                                                 int K, int N) {
    __shared__ float As[64][32];
    const int t    = threadIdx.x;
    const int lane = t & 63;
    const int mg   = t >> 6;
    const int colbase = blockIdx.x * 128 + lane * 2;
    const int kchunk  = K / gridDim.y;
    const int ks      = blockIdx.y * kchunk;

    float2 acc[16];
#pragma unroll
    for (int mm = 0; mm < 16; ++mm) acc[mm] = make_float2(0.f, 0.f);

    for (int k0 = ks; k0 < ks + kchunk; k0 += 32) {
        __syncthreads();
#pragma unroll
        for (int i = 0; i < 2; ++i) {
            int f4  = t + i * 256;
            int row = f4 >> 3, c4 = f4 & 7;
            *(float4*)&As[row][c4 * 4] =
                *(const float4*)(A + (size_t)row * K + k0 + c4 * 4);
        }
        __syncthreads();
#pragma unroll
        for (int kk = 0; kk < 32; kk += 4) {
            float2 b0 = *(const float2*)(B + (size_t)(k0 + kk + 0) * N + colbase);
            float2 b1 = *(const float2*)(B + (size_t)(k0 + kk + 1) * N + colbase);
            float2 b2 = *(const float2*)(B + (size_t)(k0 + kk + 2) * N + colbase);
            float2 b3 = *(const float2*)(B + (size_t)(k0 + kk + 3) * N + colbase);
#pragma unroll
            for (int mm = 0; mm < 16; ++mm) {
                float4 a = *(const float4*)&As[mg * 16 + mm][kk];
                acc[mm].x = fmaf(a.x, b0.x, acc[mm].x);
                acc[mm].y = fmaf(a.x, b0.y, acc[mm].y);
                acc[mm].x = fmaf(a.y, b1.x, acc[mm].x);
                acc[mm].y = fmaf(a.y, b1.y, acc[mm].y);
                acc[mm].x = fmaf(a.z, b2.x, acc[mm].x);
                acc[mm].y = fmaf(a.z, b2.y, acc[mm].y);
                acc[mm].x = fmaf(a.w, b3.x, acc[mm].x);
                acc[mm].y = fmaf(a.w, b3.y, acc[mm].y);
            }
        }
    }
    float* Pb = P + (size_t)blockIdx.y * 64 * N;
#pragma unroll
    for (int mm = 0; mm < 16; ++mm)
        *(float2*)(Pb + (size_t)(mg * 16 + mm) * N + colbase) = acc[mm];
}

__global__ __launch_bounds__(256) void reduce_add(const float* __restrict__ P,
                                                  const float* __restrict__ bias,
                                                  float* __restrict__ C,
                                                  int N, int nparts) {
    const int i4     = blockIdx.x * 256 + threadIdx.x;
    const int total4 = 64 * N / 4;
    const int col4   = i4 % (N / 4);
    float4 s = ((const float4*)bias)[col4];
    for (int k = 0; k < nparts; ++k) {
        float4 p = ((const float4*)P)[(size_t)k * total4 + i4];
        s.x += p.x; s.y += p.y; s.z += p.z; s.w += p.w;
    }
    ((float4*)C)[i4] = s;
}

// ---------------------------------------------------------------------------
// Paged attention, stage 1: full-row streaming chunks.
// One block = one chunk of 8 cache blocks (128 tokens) of ONE seq, ALL heads.
// Token row = 2048 consecutive floats (8 KB): thread t covers dims t*4 (round
// 0, head t>>4) and 1024+t*4 (round 1, head 16+(t>>4)) -> block-level reads
// are fully contiguous. Score reduce = 4x shfl_xor within 16-lane groups.
// Two independent online-softmax chains per thread (ILP). Partials
// (m,l per head; acc[2048]) -> workspace; merged in stage 2.
// ---------------------------------------------------------------------------
__global__ __launch_bounds__(256, 6) void attn_row(
        const float* __restrict__ qkv,
        const float* __restrict__ kcache,
        const float* __restrict__ vcache,
        const int* __restrict__ btab,
        const int* __restrict__ clens,
        float* __restrict__ ml,        // [S][MAXCH][H][2]
        float* __restrict__ pacc) {    // [S][MAXCH][2048]
    const int s   = blockIdx.x >> 4;
    const int c   = blockIdx.x & 15;
    const int ctx = clens[s];
    const int nb  = (ctx + 15) >> 4;
    const int cb0 = c * CHUNK_CB;
    if (cb0 >= nb) return;                  // empty chunk
    const int cb1 = min(cb0 + CHUNK_CB, nb);
    const int t   = threadIdx.x;

    const float* qb = qkv + (size_t)s * QKV_N;
    const float4 q0 = *(const float4*)(qb + t * 4);
    const float4 q1 = *(const float4*)(qb + 1024 + t * 4);

    float m0 = -1e30f, l0 = 0.f, m1 = -1e30f, l1 = 0.f;
    float4 a0 = make_float4(0.f, 0.f, 0.f, 0.f);
    float4 a1 = make_float4(0.f, 0.f, 0.f, 0.f);

    const int* bt = btab + s * BPS_;
    for (int cb = cb0; cb < cb1; ++cb) {
        const int blk = bt[cb];
        const float* kb = kcache + (size_t)blk * (BS_ * H_ * D_);
        const float* vb = vcache + (size_t)blk * (BS_ * H_ * D_);
#pragma unroll 2
        for (int i = 0; i < 16; ++i) {
            const int   tok = cb * 16 + i;
            const int   off = i * 2048 + t * 4;
            const float4 k0 = *(const float4*)(kb + off);
            const float4 k1 = *(const float4*)(kb + off + 1024);
            const float4 v0 = *(const float4*)(vb + off);
            const float4 v1 = *(const float4*)(vb + off + 1024);

            float p0 = q0.x * k0.x + q0.y * k0.y + q0.z * k0.z + q0.w * k0.w;
            float p1 = q1.x * k1.x + q1.y * k1.y + q1.z * k1.z + q1.w * k1.w;
            p0 += __shfl_xor(p0, 1);  p1 += __shfl_xor(p1, 1);
            p0 += __shfl_xor(p0, 2);  p1 += __shfl_xor(p1, 2);
            p0 += __shfl_xor(p0, 4);  p1 += __shfl_xor(p1, 4);
            p0 += __shfl_xor(p0, 8);  p1 += __shfl_xor(p1, 8);

            const bool ok = tok < ctx;
            const float s0 = ok ? p0 * 0.125f : -1e38f;
            const float s1 = ok ? p1 * 0.125f : -1e38f;

            const float nm0 = fmaxf(m0, s0);
            const float r0  = __expf(m0 - nm0);
            const float e0  = __expf(s0 - nm0);
            m0 = nm0;
            l0 = fmaf(l0, r0, e0);
            a0.x = fmaf(e0, v0.x, a0.x * r0);
            a0.y = fmaf(e0, v0.y, a0.y * r0);
            a0.z = fmaf(e0, v0.z, a0.z * r0);
            a0.w = fmaf(e0, v0.w, a0.w * r0);

            const float nm1 = fmaxf(m1, s1);
            const float r1  = __expf(m1 - nm1);
            const float e1  = __expf(s1 - nm1);
            m1 = nm1;
            l1 = fmaf(l1, r1, e1);
            a1.x = fmaf(e1, v1.x, a1.x * r1);
            a1.y = fmaf(e1, v1.y, a1.y * r1);
            a1.z = fmaf(e1, v1.z, a1.z * r1);
            a1.w = fmaf(e1, v1.w, a1.w * r1);
        }
    }

    const int slot = s * MAXCH + c;
    *(float4*)&pacc[(size_t)slot * 2048 + t * 4]        = a0;
    *(float4*)&pacc[(size_t)slot * 2048 + 1024 + t * 4] = a1;
    if ((t & 15) == 0) {
        const int h0 = t >> 4;              // round-0 head
        ml[((size_t)slot * 32 + h0) * 2 + 0]        = m0;
        ml[((size_t)slot * 32 + h0) * 2 + 1]        = l0;
        ml[((size_t)slot * 32 + 16 + h0) * 2 + 0]   = m1;
        ml[((size_t)slot * 32 + 16 + h0) * 2 + 1]   = l1;
    }
}

// ---------------------------------------------------------------------------
// Paged attention, stage 2: merge <=16 chunk partials + the new token.
// One wave per (seq, head); thread d owns output dim d.
// ---------------------------------------------------------------------------
__global__ __launch_bounds__(64) void attn_merge(
        const float* __restrict__ qkv,
        const int* __restrict__ clens,
        const float* __restrict__ ml,
        const float* __restrict__ pacc,
        float* __restrict__ attn) {
    const int sh = blockIdx.x;
    const int s  = sh >> 5;
    const int h  = sh & 31;
    const int d  = threadIdx.x;
    const int ctx = clens[s];
    const int nb  = (ctx + 15) >> 4;
    const int nch = (nb + CHUNK_CB - 1) / CHUNK_CB;

    float M = -1e30f, L = 0.f, O = 0.f;
    for (int c = 0; c < nch; ++c) {
        const int slot = s * MAXCH + c;
        const float mc = ml[((size_t)slot * 32 + h) * 2 + 0];
        const float lc = ml[((size_t)slot * 32 + h) * 2 + 1];
        const float oc = pacc[(size_t)slot * 2048 + h * 64 + d];
        const float nm = fmaxf(M, mc);
        const float ra = __expf(M - nm);
        const float rb = __expf(mc - nm);
        O = O * ra + oc * rb;
        L = L * ra + lc * rb;
        M = nm;
    }

    // current token (position L_, always attended)
    const float qd = qkv[(size_t)s * QKV_N + h * 64 + d];
    const float kd = qkv[(size_t)s * QKV_N + E_ + h * 64 + d];
    float part = qd * kd;
#pragma unroll
    for (int msk = 1; msk <= 32; msk <<= 1) part += __shfl_xor(part, msk);
    const float score = part * 0.125f;
    const float nm = fmaxf(M, score);
    const float r  = __expf(M - nm);
    const float p  = __expf(score - nm);
    const float vd = qkv[(size_t)s * QKV_N + 2 * E_ + h * 64 + d];
    O = O * r + p * vd;
    L = L * r + p;

    attn[(size_t)s * E_ + h * 64 + d] = O / L;
}

// ---------------------------------------------------------------------------
extern "C" void kernel_launch(void* const* d_in, const int* in_sizes, int n_in,
                              void* d_out, int out_size, void* d_ws, size_t ws_size,
                              hipStream_t stream) {
    const float* hidden = (const float*)d_in[0];
    const float* wqkv   = (const float*)d_in[1];
    const float* bqkv   = (const float*)d_in[2];
    const float* wout   = (const float*)d_in[3];
    const float* bout   = (const float*)d_in[4];
    const float* kcache = (const float*)d_in[5];
    const float* vcache = (const float*)d_in[6];
    const int*   btab   = (const int*)d_in[7];
    const int*   clens  = (const int*)d_in[8];
    float* out = (float*)d_out;

    float* qkv     = (float*)d_ws;                        // [64, 6144]
    float* attnbuf = qkv + (size_t)S_ * QKV_N;            // [64, 2048]
    float* part1   = attnbuf + (size_t)S_ * E_;           // [8][64][6144]
    float* part2   = part1 + (size_t)8 * S_ * QKV_N;      // [16][64][2048]
    // lifetime aliasing: part1 is dead after reduce_add(1); part2 is not
    // written until gemm_part(3). attn partials reuse that space.
    float* pacc    = part1;                               // [64][16][2048]
    float* ml      = part2;                               // [64][16][32][2]

    // 1) QKV projection: partials (KSPLIT=8) then reduce+bias
    gemm_part<<<dim3(QKV_N / 128, 8), 256, 0, stream>>>(hidden, wqkv, part1,
                                                        E_, QKV_N);
    reduce_add<<<dim3(S_ * QKV_N / 4 / 256), 256, 0, stream>>>(part1, bqkv,
                                                               qkv, QKV_N, 8);
    // 2a) full-row chunked attention -> partials
    attn_row<<<dim3(S_ * MAXCH), 256, 0, stream>>>(qkv, kcache, vcache,
                                                   btab, clens, ml, pacc);
    // 2b) merge partials + new token -> attnbuf [64, 2048]
    attn_merge<<<dim3(S_ * H_), 64, 0, stream>>>(qkv, clens, ml, pacc, attnbuf);
    // 3) output projection: partials (KSPLIT=16) then reduce+bias
    gemm_part<<<dim3(E_ / 128, 16), 256, 0, stream>>>(attnbuf, wout, part2,
                                                      E_, E_);
    reduce_add<<<dim3(S_ * E_ / 4 / 256), 256, 0, stream>>>(part2, bout,
                                                            out, E_, 16);
}